// Round 1
// 210.469 us; speedup vs baseline: 1.0036x; 1.0036x over previous
//
#include <hip/hip_runtime.h>
#include <hip/hip_bf16.h>
#include <stdint.h>

typedef unsigned short u16;
typedef __attribute__((ext_vector_type(8))) short short8;
typedef __attribute__((ext_vector_type(4))) float f32x4;

#define BATCH 4096
#define DIN   1024
#define NH    1024
#define KTOT  2048

__device__ __forceinline__ void gload_lds16(const void* gp, void* lp) {
    __builtin_amdgcn_global_load_lds(
        (const __attribute__((address_space(1))) uint32_t*)gp,
        (__attribute__((address_space(3))) uint32_t*)lp, 16, 0, 0);
}

__device__ __forceinline__ u16 f2bf(float f) {   // round-to-nearest-even
    uint32_t t; __builtin_memcpy(&t, &f, 4);
    uint32_t r = (t + 0x7FFFu + ((t >> 16) & 1u)) >> 16;
    return (u16)r;
}
__device__ __forceinline__ float hsig(float z) {
    return fminf(fmaxf(fmaf(z, 0.2f, 0.5f), 0.0f), 1.0f);
}
__device__ __forceinline__ float fast_tanh(float x) {
    x = fminf(fmaxf(x, -12.0f), 12.0f);
    float e = __expf(2.0f * x);
    return (e - 1.0f) / (e + 1.0f);
}

// ---------------------------------------------------------------------------
// Fused prep kernel (unchanged from R10):
//   blocks [0, 2048):      weight cast+transpose+concat -> Bt[(g*NH+n)][KTOT]
//   blocks [2048, 18432):  activation cast+concat       -> Abuf[m][KTOT]
// ---------------------------------------------------------------------------
#define WT_BLOCKS 2048
__global__ __launch_bounds__(256) void prep_kernel(
    const float* __restrict__ x, const float* __restrict__ h0,
    const float* __restrict__ Wf, const float* __restrict__ Wi,
    const float* __restrict__ Wo, const float* __restrict__ Wc,
    const float* __restrict__ Uf, const float* __restrict__ Ui,
    const float* __restrict__ Uo, const float* __restrict__ Uc,
    u16* __restrict__ Bt, u16* __restrict__ Abuf)
{
    __shared__ u16 tile[64][65];
    const int bid = blockIdx.x;
    const int tid = threadIdx.x;

    if (bid < WT_BLOCKS) {
        const int mz = bid >> 8;
        const float* srcs[8] = {Wf, Wi, Wo, Wc, Uf, Ui, Uo, Uc};
        const float* src = srcs[mz];
        const int g    = mz & 3;
        const int koff = (mz >> 2) << 10;
        const int k0 = ((bid >> 4) & 15) * 64;
        const int n0 = (bid & 15) * 64;

#pragma unroll
        for (int i = 0; i < 4; i++) {
            int idx = i * 256 + tid;
            int kk = idx >> 4, c = idx & 15;
            float4 v = *(const float4*)(src + (size_t)(k0 + kk) * NH + n0 + c * 4);
            u16* dst = &tile[kk][c * 4];
            dst[0] = f2bf(v.x); dst[1] = f2bf(v.y);
            dst[2] = f2bf(v.z); dst[3] = f2bf(v.w);
        }
        __syncthreads();
#pragma unroll
        for (int i = 0; i < 2; i++) {
            int idx = i * 256 + tid;
            int nn = idx >> 3, c = idx & 7;
            union { u16 v[8]; uint4 q; } pk;
#pragma unroll
            for (int j = 0; j < 8; j++) pk.v[j] = tile[c * 8 + j][nn];
            *(uint4*)(Bt + ((size_t)(g * NH + n0 + nn)) * KTOT + koff + k0 + c * 8) = pk.q;
        }
    } else {
        const int c  = (bid - WT_BLOCKS) * 256 + tid;
        const int m  = c >> 8;
        const int kc = (c & 255) * 8;
        const float* src = (kc < DIN) ? (x + (size_t)m * DIN + kc)
                                      : (h0 + (size_t)m * DIN + (kc - DIN));
        float4 v0 = *(const float4*)(src);
        float4 v1 = *(const float4*)(src + 4);
        union { u16 v[8]; uint4 q; } pk;
        pk.v[0] = f2bf(v0.x); pk.v[1] = f2bf(v0.y);
        pk.v[2] = f2bf(v0.z); pk.v[3] = f2bf(v0.w);
        pk.v[4] = f2bf(v1.x); pk.v[5] = f2bf(v1.y);
        pk.v[6] = f2bf(v1.z); pk.v[7] = f2bf(v1.w);
        *(uint4*)(Abuf + (size_t)m * KTOT + kc) = pk.q;
    }
}

// ---------------------------------------------------------------------------
// R11 GEMM: 256m x (64n x 4g) tile, BK=32, ring-4 LDS (128 KiB), 8 waves
// (2m x 4n), per-wave output 128m x 16n x 4g (acc[8][4]).
// T3+T4: one raw s_barrier per K-tile, counted s_waitcnt vmcnt(8) (never 0
// in-loop), tile T+3 staged during iter T -> 3-iteration issue-to-deadline.
// Race ledger:
//   stage(T+3) writes slot (T-1)&3, last read iter T-1; those ds_reads
//   complete before iter T-1's MFMA (compiler lgkm) which precedes its
//   barrier, which precedes iter T's stage issues in all waves.  vmcnt(8)
//   at end of iter T leaves exactly tiles T+2,T+3 (4 issues each) in
//   flight, so tile T+1 is landed before any wave's iter T+1 ds_reads.
// LDS swizzle: 64-B rows, 16-B chunk c stored at c ^ ((row>>1)&3) via
// pre-swizzled global source (gload_lds writes linearly); read side applies
// the same XOR -> bank-group map is bijective per 8-lane phase (<=2-way).
// ---------------------------------------------------------------------------
#define BM   256
#define BNG  64            // n-cols per gate per block (4 gates -> 256 eff.)
#define BK   32
#define NT   (KTOT / BK)   // 64 K-tiles
#define TILE_ELEMS (BM * BK)   // 8192 u16 = 16 KB per tile per matrix

__global__ __launch_bounds__(512, 2) void lstm_gemm_kernel(
    const u16* __restrict__ Abuf, const float* __restrict__ c0,
    const u16* __restrict__ Bt,
    const float* __restrict__ bfv, const float* __restrict__ biv,
    const float* __restrict__ bov, const float* __restrict__ bcv,
    float* __restrict__ out)
{
    extern __shared__ u16 smem[];            // 128 KiB dynamic LDS
    u16* As = smem;                          // [4][256][32]
    u16* Bs = smem + 4 * TILE_ELEMS;         // [4][256][32], rows = g*64+n

    const int tid  = threadIdx.x;
    const int wv   = tid >> 6;
    const int lane = tid & 63;
    const int wm = wv >> 2;                  // 0..1  (m half)
    const int wn = wv & 3;                   // 0..3  (16-col slice per gate)
    const int m0 = blockIdx.x * BM;
    const int n0 = blockIdx.y * BNG;

    // ---- staging roles: wave issue i covers LDS rows i*16..+16 (1 KB) ----
    const int si = wv * 2;
    const int sr = lane >> 2;                          // row within 16
    const int kc = (((lane & 3) ^ ((lane >> 3) & 3)) << 3); // pre-swizzled k
    const int rA0 = si * 16 + sr, rA1 = rA0 + 16;
    const u16* aS0 = Abuf + (size_t)(m0 + rA0) * KTOT + kc;
    const u16* aS1 = Abuf + (size_t)(m0 + rA1) * KTOT + kc;
    const u16* bS0 = Bt + (size_t)((rA0 >> 6) * NH + n0 + (rA0 & 63)) * KTOT + kc;
    const u16* bS1 = Bt + (size_t)((rA1 >> 6) * NH + n0 + (rA1 & 63)) * KTOT + kc;
    const int ldsA0 = si * 512, ldsA1 = ldsA0 + 512;   // elems within a slot

    // ---- fragment-read offsets (loop-invariant) ----
    const int am   = lane & 15;
    const int quad = lane >> 4;
    const int pchunk = ((quad ^ ((am >> 1) & 3)) << 3);   // un-swizzle
    int aOff[8], bOff[4];
#pragma unroll
    for (int mt = 0; mt < 8; mt++)
        aOff[mt] = (wm * 128 + mt * 16 + am) * BK + pchunk;
#pragma unroll
    for (int g = 0; g < 4; g++)
        bOff[g] = (g * 64 + wn * 16 + am) * BK + pchunk;

    f32x4 acc[8][4];
#pragma unroll
    for (int mt = 0; mt < 8; mt++)
#pragma unroll
        for (int g = 0; g < 4; g++)
            acc[mt][g] = (f32x4){0.f, 0.f, 0.f, 0.f};

    auto stage = [&](int S) {                // 4 gload_lds issues / thread
        const int slot = S & 3;
        const size_t ko = (size_t)S * BK;
        u16* ad = As + slot * TILE_ELEMS;
        u16* bd = Bs + slot * TILE_ELEMS;
        gload_lds16(aS0 + ko, ad + ldsA0);
        gload_lds16(aS1 + ko, ad + ldsA1);
        gload_lds16(bS0 + ko, bd + ldsA0);
        gload_lds16(bS1 + ko, bd + ldsA1);
    };

    // ---- prologue: 3 tiles in flight; ensure tile 0 landed (8 = tiles 1,2)
    stage(0); asm volatile("" ::: "memory");
    stage(1); asm volatile("" ::: "memory");
    stage(2);
    asm volatile("s_waitcnt vmcnt(8)" ::: "memory");
    asm volatile("s_barrier" ::: "memory");

    for (int T = 0; T < NT; ++T) {
        const u16* as = As + (T & 3) * TILE_ELEMS;
        const u16* bs = Bs + (T & 3) * TILE_ELEMS;
        short8 a[8], b[4];
#pragma unroll
        for (int mt = 0; mt < 8; mt++)
            a[mt] = *(const short8*)(as + aOff[mt]);
#pragma unroll
        for (int g = 0; g < 4; g++)
            b[g] = *(const short8*)(bs + bOff[g]);

        if (T < NT - 3) stage(T + 3);

        __builtin_amdgcn_s_setprio(1);
#pragma unroll
        for (int g = 0; g < 4; g++)
#pragma unroll
            for (int mt = 0; mt < 8; mt++)
                acc[mt][g] = __builtin_amdgcn_mfma_f32_16x16x32_bf16(
                    a[mt], b[g], acc[mt][g], 0, 0, 0);
        __builtin_amdgcn_s_setprio(0);

        asm volatile("s_waitcnt vmcnt(8)" ::: "memory");
        asm volatile("s_barrier" ::: "memory");
    }

    // ---- epilogue: C/D layout col=lane&15, row=quad*4+reg ----
    const int col = n0 + wn * 16 + am;
    const float b0 = bfv[col], b1 = biv[col], b2 = bov[col], b3 = bcv[col];
    const size_t HN = (size_t)BATCH * NH;

#pragma unroll
    for (int mt = 0; mt < 8; mt++) {
#pragma unroll
        for (int r = 0; r < 4; r++) {
            const int row = m0 + wm * 128 + mt * 16 + quad * 4 + r;
            const size_t off = (size_t)row * NH + col;
            float zf = acc[mt][0][r] + b0;
            float zi = acc[mt][1][r] + b1;
            float zo = acc[mt][2][r] + b2;
            float zc = acc[mt][3][r] + b3;
            float fg = hsig(zf), ig = hsig(zi), og = hsig(zo);
            float ct = fast_tanh(zc);
            float cn = fg * c0[off] + ig * ct;
            float hn = og * fast_tanh(cn);
            out[off]          = hn;   // h
            out[HN + off]     = cn;   // c
            out[2 * HN + off] = hn;   // h (duplicate output)
        }
    }
}

extern "C" void kernel_launch(void* const* d_in, const int* in_sizes, int n_in,
                              void* d_out, int out_size, void* d_ws, size_t ws_size,
                              hipStream_t stream) {
    const float* x  = (const float*)d_in[0];
    const float* c0 = (const float*)d_in[1];
    const float* h0 = (const float*)d_in[2];
    const float* Wf = (const float*)d_in[3];
    const float* Wi = (const float*)d_in[4];
    const float* Wo = (const float*)d_in[5];
    const float* Wc = (const float*)d_in[6];
    const float* Uf = (const float*)d_in[7];
    const float* Ui = (const float*)d_in[8];
    const float* Uo = (const float*)d_in[9];
    const float* Uc = (const float*)d_in[10];
    const float* bf = (const float*)d_in[11];
    const float* bi = (const float*)d_in[12];
    const float* bo = (const float*)d_in[13];
    const float* bc = (const float*)d_in[14];

    u16* Bt   = (u16*)d_ws;                          // 4096 x 2048 bf16 = 16 MB
    u16* Abuf = (u16*)d_ws + (size_t)4 * NH * KTOT;  // 4096 x 2048 bf16 = 16 MB

    static bool attr_done = false;
    if (!attr_done) {
        (void)hipFuncSetAttribute((const void*)lstm_gemm_kernel,
                                  hipFuncAttributeMaxDynamicSharedMemorySize,
                                  131072);
        attr_done = true;
    }

    prep_kernel<<<WT_BLOCKS + (BATCH * KTOT / 8) / 256, 256, 0, stream>>>(
        x, h0, Wf, Wi, Wo, Wc, Uf, Ui, Uo, Uc, Bt, Abuf);

    dim3 gg(BATCH / BM, NH / BNG);   // 16 x 16 = 256 blocks, 1/CU, 8 waves/CU
    lstm_gemm_kernel<<<gg, 512, 131072, stream>>>(Abuf, c0, Bt, bf, bi, bo, bc,
                                                  (float*)d_out);
}

// Round 2
// 209.057 us; speedup vs baseline: 1.0104x; 1.0068x over previous
//
#include <hip/hip_runtime.h>
#include <hip/hip_bf16.h>
#include <stdint.h>

typedef unsigned short u16;
typedef __attribute__((ext_vector_type(8))) short short8;
typedef __attribute__((ext_vector_type(4))) float f32x4;

#define BATCH 4096
#define DIN   1024
#define NH    1024
#define KTOT  2048

__device__ __forceinline__ void gload_lds16(const void* gp, void* lp) {
    __builtin_amdgcn_global_load_lds(
        (const __attribute__((address_space(1))) uint32_t*)gp,
        (__attribute__((address_space(3))) uint32_t*)lp, 16, 0, 0);
}

__device__ __forceinline__ u16 f2bf(float f) {   // round-to-nearest-even
    uint32_t t; __builtin_memcpy(&t, &f, 4);
    uint32_t r = (t + 0x7FFFu + ((t >> 16) & 1u)) >> 16;
    return (u16)r;
}
__device__ __forceinline__ float hsig(float z) {
    return fminf(fmaxf(fmaf(z, 0.2f, 0.5f), 0.0f), 1.0f);
}
__device__ __forceinline__ float fast_tanh(float x) {
    x = fminf(fmaxf(x, -12.0f), 12.0f);
    float e = __expf(2.0f * x);
    return (e - 1.0f) / (e + 1.0f);
}

// ---------------------------------------------------------------------------
// Fused prep kernel (unchanged):
//   blocks [0, 2048):      weight cast+transpose+concat -> Bt[(g*NH+n)][KTOT]
//   blocks [2048, 18432):  activation cast+concat       -> Abuf[m][KTOT]
// ---------------------------------------------------------------------------
#define WT_BLOCKS 2048
__global__ __launch_bounds__(256) void prep_kernel(
    const float* __restrict__ x, const float* __restrict__ h0,
    const float* __restrict__ Wf, const float* __restrict__ Wi,
    const float* __restrict__ Wo, const float* __restrict__ Wc,
    const float* __restrict__ Uf, const float* __restrict__ Ui,
    const float* __restrict__ Uo, const float* __restrict__ Uc,
    u16* __restrict__ Bt, u16* __restrict__ Abuf)
{
    __shared__ u16 tile[64][65];
    const int bid = blockIdx.x;
    const int tid = threadIdx.x;

    if (bid < WT_BLOCKS) {
        const int mz = bid >> 8;
        const float* srcs[8] = {Wf, Wi, Wo, Wc, Uf, Ui, Uo, Uc};
        const float* src = srcs[mz];
        const int g    = mz & 3;
        const int koff = (mz >> 2) << 10;
        const int k0 = ((bid >> 4) & 15) * 64;
        const int n0 = (bid & 15) * 64;

#pragma unroll
        for (int i = 0; i < 4; i++) {
            int idx = i * 256 + tid;
            int kk = idx >> 4, c = idx & 15;
            float4 v = *(const float4*)(src + (size_t)(k0 + kk) * NH + n0 + c * 4);
            u16* dst = &tile[kk][c * 4];
            dst[0] = f2bf(v.x); dst[1] = f2bf(v.y);
            dst[2] = f2bf(v.z); dst[3] = f2bf(v.w);
        }
        __syncthreads();
#pragma unroll
        for (int i = 0; i < 2; i++) {
            int idx = i * 256 + tid;
            int nn = idx >> 3, c = idx & 7;
            union { u16 v[8]; uint4 q; } pk;
#pragma unroll
            for (int j = 0; j < 8; j++) pk.v[j] = tile[c * 8 + j][nn];
            *(uint4*)(Bt + ((size_t)(g * NH + n0 + nn)) * KTOT + koff + k0 + c * 8) = pk.q;
        }
    } else {
        const int c  = (bid - WT_BLOCKS) * 256 + tid;
        const int m  = c >> 8;
        const int kc = (c & 255) * 8;
        const float* src = (kc < DIN) ? (x + (size_t)m * DIN + kc)
                                      : (h0 + (size_t)m * DIN + (kc - DIN));
        float4 v0 = *(const float4*)(src);
        float4 v1 = *(const float4*)(src + 4);
        union { u16 v[8]; uint4 q; } pk;
        pk.v[0] = f2bf(v0.x); pk.v[1] = f2bf(v0.y);
        pk.v[2] = f2bf(v0.z); pk.v[3] = f2bf(v0.w);
        pk.v[4] = f2bf(v1.x); pk.v[5] = f2bf(v1.y);
        pk.v[6] = f2bf(v1.z); pk.v[7] = f2bf(v1.w);
        *(uint4*)(Abuf + (size_t)m * KTOT + kc) = pk.q;
    }
}

// ---------------------------------------------------------------------------
// R12 GEMM: same geometry as R11 (256m x (64n x 4g), BK=32, ring-4 LDS,
// 8 waves 2m x 4n, acc[8][4]) with two fixes:
//  (1) sync idiom: __builtin_amdgcn_s_barrier() + NAKED asm vmcnt(N).
//      R11 used "memory"-clobbered asm; the memory legalizer inserted a
//      full vmcnt(0) lgkmcnt(0) drain before each -> identical 79 us.
//  (2) register double-buffered fragments: ds_reads for tile T+1 are issued
//      alongside tile T's MFMA cluster, so the LDS pipe (~1400 cyc/tile)
//      overlaps the MFMA pipe (~1240 cyc/tile) instead of adding serially.
// Sync ledger (per-wave stage = 4 vm issues):
//   prologue: stage 0,1,2; vmcnt(4) -> tiles 0,1 landed; barrier.
//   iter T:   loadFrags(T+1)   [tiles <= T+1 landed by invariant]
//             stage(T+3)       [writes slot (T-1)&3; its last readers were
//                               loadFrags(T-1) in iter T-2, whose lgkm waits
//                               precede iter T-1's MFMA < end-of-(T-1)
//                               barrier < this issue, all waves]
//             MFMA(frags T)    [regs loaded in iter T-1]
//             vmcnt(4)         [outstanding: stage(T+3) only -> tiles <= T+2
//                               landed], s_barrier -> invariant for T+1.
// ---------------------------------------------------------------------------
#define BM   256
#define BNG  64            // n-cols per gate per block (4 gates -> 256 eff.)
#define BK   32
#define NT   (KTOT / BK)   // 64 K-tiles
#define TILE_ELEMS (BM * BK)   // 8192 u16 = 16 KB per tile per matrix

__global__ __launch_bounds__(512, 2) void lstm_gemm_kernel(
    const u16* __restrict__ Abuf, const float* __restrict__ c0,
    const u16* __restrict__ Bt,
    const float* __restrict__ bfv, const float* __restrict__ biv,
    const float* __restrict__ bov, const float* __restrict__ bcv,
    float* __restrict__ out)
{
    extern __shared__ u16 smem[];            // 128 KiB dynamic LDS
    u16* As = smem;                          // [4][256][32]
    u16* Bs = smem + 4 * TILE_ELEMS;         // [4][256][32], rows = g*64+n

    const int tid  = threadIdx.x;
    const int wv   = tid >> 6;
    const int lane = tid & 63;
    const int wm = wv >> 2;                  // 0..1  (m half)
    const int wn = wv & 3;                   // 0..3  (16-col slice per gate)
    const int m0 = blockIdx.x * BM;
    const int n0 = blockIdx.y * BNG;

    // ---- staging roles: wave issue i covers LDS rows i*16..+16 (1 KB) ----
    const int si = wv * 2;
    const int sr = lane >> 2;                          // row within 16
    const int kc = (((lane & 3) ^ ((lane >> 3) & 3)) << 3); // pre-swizzled k
    const int rA0 = si * 16 + sr, rA1 = rA0 + 16;
    const u16* aS0 = Abuf + (size_t)(m0 + rA0) * KTOT + kc;
    const u16* aS1 = Abuf + (size_t)(m0 + rA1) * KTOT + kc;
    const u16* bS0 = Bt + (size_t)((rA0 >> 6) * NH + n0 + (rA0 & 63)) * KTOT + kc;
    const u16* bS1 = Bt + (size_t)((rA1 >> 6) * NH + n0 + (rA1 & 63)) * KTOT + kc;
    const int ldsA0 = si * 512, ldsA1 = ldsA0 + 512;   // elems within a slot

    // ---- fragment-read offsets (loop-invariant) ----
    const int am   = lane & 15;
    const int quad = lane >> 4;
    const int pchunk = ((quad ^ ((am >> 1) & 3)) << 3);   // un-swizzle
    int aOff[8], bOff[4];
#pragma unroll
    for (int mt = 0; mt < 8; mt++)
        aOff[mt] = (wm * 128 + mt * 16 + am) * BK + pchunk;
#pragma unroll
    for (int g = 0; g < 4; g++)
        bOff[g] = (g * 64 + wn * 16 + am) * BK + pchunk;

    f32x4 acc[8][4];
#pragma unroll
    for (int mt = 0; mt < 8; mt++)
#pragma unroll
        for (int g = 0; g < 4; g++)
            acc[mt][g] = (f32x4){0.f, 0.f, 0.f, 0.f};

    auto stage = [&](int S) {                // 4 gload_lds issues / thread
        const int slot = S & 3;
        const size_t ko = (size_t)S * BK;
        u16* ad = As + slot * TILE_ELEMS;
        u16* bd = Bs + slot * TILE_ELEMS;
        gload_lds16(aS0 + ko, ad + ldsA0);
        gload_lds16(aS1 + ko, ad + ldsA1);
        gload_lds16(bS0 + ko, bd + ldsA0);
        gload_lds16(bS1 + ko, bd + ldsA1);
    };
    auto loadFrags = [&](int t, short8 (&fa)[8], short8 (&fb)[4]) {
        const u16* as = As + (t & 3) * TILE_ELEMS;
        const u16* bs = Bs + (t & 3) * TILE_ELEMS;
#pragma unroll
        for (int mt = 0; mt < 8; mt++)
            fa[mt] = *(const short8*)(as + aOff[mt]);
#pragma unroll
        for (int g = 0; g < 4; g++)
            fb[g] = *(const short8*)(bs + bOff[g]);
    };
    auto mfmaStep = [&](short8 (&fa)[8], short8 (&fb)[4]) {
        __builtin_amdgcn_s_setprio(1);
#pragma unroll
        for (int g = 0; g < 4; g++)
#pragma unroll
            for (int mt = 0; mt < 8; mt++)
                acc[mt][g] = __builtin_amdgcn_mfma_f32_16x16x32_bf16(
                    fa[mt], fb[g], acc[mt][g], 0, 0, 0);
        __builtin_amdgcn_s_setprio(0);
    };

    short8 fA0[8], fB0[4], fA1[8], fB1[4];

    // ---- prologue: 3 tiles in flight; tiles 0,1 landed, tile 2 flying ----
    stage(0);
    stage(1);
    stage(2);
    asm volatile("s_waitcnt vmcnt(4)");
    __builtin_amdgcn_s_barrier();
    loadFrags(0, fA0, fB0);

    for (int T = 0; T < NT; T += 2) {
        // even sub-iter: compute tile T, prefetch frags T+1, stage T+3
        loadFrags(T + 1, fA1, fB1);
        if (T + 3 < NT) stage(T + 3);
        mfmaStep(fA0, fB0);
        asm volatile("s_waitcnt vmcnt(4)");
        __builtin_amdgcn_s_barrier();

        // odd sub-iter: compute tile T+1, prefetch frags T+2, stage T+4
        if (T + 2 < NT) loadFrags(T + 2, fA0, fB0);
        if (T + 4 < NT) stage(T + 4);
        mfmaStep(fA1, fB1);
        asm volatile("s_waitcnt vmcnt(4)");
        __builtin_amdgcn_s_barrier();
    }

    // ---- epilogue: C/D layout col=lane&15, row=quad*4+reg ----
    const int col = n0 + wn * 16 + am;
    const float b0 = bfv[col], b1 = biv[col], b2 = bov[col], b3 = bcv[col];
    const size_t HN = (size_t)BATCH * NH;

#pragma unroll
    for (int mt = 0; mt < 8; mt++) {
#pragma unroll
        for (int r = 0; r < 4; r++) {
            const int row = m0 + wm * 128 + mt * 16 + quad * 4 + r;
            const size_t off = (size_t)row * NH + col;
            float zf = acc[mt][0][r] + b0;
            float zi = acc[mt][1][r] + b1;
            float zo = acc[mt][2][r] + b2;
            float zc = acc[mt][3][r] + b3;
            float fg = hsig(zf), ig = hsig(zi), og = hsig(zo);
            float ct = fast_tanh(zc);
            float cn = fg * c0[off] + ig * ct;
            float hn = og * fast_tanh(cn);
            out[off]          = hn;   // h
            out[HN + off]     = cn;   // c
            out[2 * HN + off] = hn;   // h (duplicate output)
        }
    }
}

extern "C" void kernel_launch(void* const* d_in, const int* in_sizes, int n_in,
                              void* d_out, int out_size, void* d_ws, size_t ws_size,
                              hipStream_t stream) {
    const float* x  = (const float*)d_in[0];
    const float* c0 = (const float*)d_in[1];
    const float* h0 = (const float*)d_in[2];
    const float* Wf = (const float*)d_in[3];
    const float* Wi = (const float*)d_in[4];
    const float* Wo = (const float*)d_in[5];
    const float* Wc = (const float*)d_in[6];
    const float* Uf = (const float*)d_in[7];
    const float* Ui = (const float*)d_in[8];
    const float* Uo = (const float*)d_in[9];
    const float* Uc = (const float*)d_in[10];
    const float* bf = (const float*)d_in[11];
    const float* bi = (const float*)d_in[12];
    const float* bo = (const float*)d_in[13];
    const float* bc = (const float*)d_in[14];

    u16* Bt   = (u16*)d_ws;                          // 4096 x 2048 bf16 = 16 MB
    u16* Abuf = (u16*)d_ws + (size_t)4 * NH * KTOT;  // 4096 x 2048 bf16 = 16 MB

    static bool attr_done = false;
    if (!attr_done) {
        (void)hipFuncSetAttribute((const void*)lstm_gemm_kernel,
                                  hipFuncAttributeMaxDynamicSharedMemorySize,
                                  131072);
        attr_done = true;
    }

    prep_kernel<<<WT_BLOCKS + (BATCH * KTOT / 8) / 256, 256, 0, stream>>>(
        x, h0, Wf, Wi, Wo, Wc, Uf, Ui, Uo, Uc, Bt, Abuf);

    dim3 gg(BATCH / BM, NH / BNG);   // 16 x 16 = 256 blocks, 1/CU, 8 waves/CU
    lstm_gemm_kernel<<<gg, 512, 131072, stream>>>(Abuf, c0, Bt, bf, bi, bo, bc,
                                                  (float*)d_out);
}